// Round 10
// baseline (153.281 us; speedup 1.0000x reference)
//
#include <hip/hip_runtime.h>
#include <hip/hip_fp16.h>

// FeatureAdaption (DCNv1). B=4, CIN=COUT=128, H=W=128, K=3, G=4, CG=32.
// Round 10: occupancy (drop dead window pad: LDS 54.4->50 KB = 3 blocks/CU),
// prep_row at grid 1024, combined bilinear weights (6->4 pk-ops/component).
//  - deform: grid 512 = (b,h) row; wave = 32 px (2 B-frags); 5-row slab,
//    xs[r5][px128][slot5(4 used)] uint4 stride-5 -> all-8-bank-group gather.
//    Records in registers (offs2 preloaded, geometry recomputed per lane).
//  - prep_row: grid 1024 half-row; stage f32->f16 LDS; x16 channel-last write
//    + offset GEMM (f16 MFMA, K=128) -> offs2 packed half2 (dy,dx).
//
// ws layout (bytes): wdef [0,294912) | woff [294912,315392)
//   | offs2 [315392,9752576) | x16 [9752576,26529792)

#define HW 16384

typedef _Float16 h2 __attribute__((ext_vector_type(2)));
typedef _Float16 h8 __attribute__((ext_vector_type(8)));
typedef float floatx4 __attribute__((ext_vector_type(4)));

static __device__ __forceinline__ unsigned pkrtz(float a, float b) {
  auto h = __builtin_amdgcn_cvt_pkrtz(a, b);
  return __builtin_bit_cast(unsigned, h);
}
static __device__ __forceinline__ h2 u2h2(unsigned u) { return __builtin_bit_cast(h2, u); }
static __device__ __forceinline__ unsigned h2u(h2 h) { return __builtin_bit_cast(unsigned, h); }
static __device__ __forceinline__ h2 splat_lo(unsigned u) {
  unsigned v = (u & 0xffffu) | (u << 16); return u2h2(v);
}
static __device__ __forceinline__ h2 splat_hi(unsigned u) {
  unsigned v = (u >> 16) | (u & 0xffff0000u); return u2h2(v);
}

// ---------------- kernel 0: weight prep ----------------
__global__ __launch_bounds__(256) void prep_w(
    const float* __restrict__ w_off, const float* __restrict__ w_def,
    _Float16* __restrict__ woff, _Float16* __restrict__ wdef) {
  int idx = blockIdx.x * 256 + threadIdx.x;
  int stride = gridDim.x * 256;
  // wdef A-frags (16x16x32): [kk9][ks4][ot8][lane64][j8]
  for (int i = idx; i < 147456; i += stride) {
    int j = i & 7, l = (i >> 3) & 63, ot = (i >> 9) & 7, ks = (i >> 12) & 3, kk = i >> 14;
    int o = ot * 16 + (l & 15);
    int c = ks * 32 + ((l >> 4) << 3) + j;
    wdef[i] = (_Float16)w_def[(o * 128 + c) * 9 + kk];
  }
  // woff A-frags (16x16x32): [ks4][mt5][lane64][j8], rows>=72 zero
  for (int i = idx; i < 10240; i += stride) {
    int j = i & 7, l = (i >> 3) & 63, t = i >> 9;
    int mt = t % 5, ks = t / 5;
    int o = mt * 16 + (l & 15);
    int c = ks * 32 + ((l >> 4) << 3) + j;
    woff[i] = (o < 72) ? (_Float16)w_off[o * 128 + c] : (_Float16)0.f;
  }
}

// ---------------- kernel 1: fused transpose + offset conv (half-row) ----------------
__global__ __launch_bounds__(256) void prep_row(
    const float* __restrict__ x, const _Float16* __restrict__ woff,
    const float* __restrict__ b_off, unsigned* __restrict__ offs2,
    _Float16* __restrict__ x16) {
  __shared__ uint2 xpk[32 * 64];    // [cq32][px64] f16 ch-quads, 16 KB
  int tid = threadIdx.x, lane = tid & 63, wv = tid >> 6;
  int i = blockIdx.x;
  int L = (i & 7) * 128 + (i >> 3); // XCD band swizzle
  int half = L & 1, h = (L >> 1) & 127, b = L >> 8;
  int p0 = half * 64;

#pragma unroll
  for (int it = 0; it < 2; it++) {
    int u = it * 256 + tid;
    int px4 = u & 15, cqq = u >> 4;   // 16 px-quads x 32 ch-quads
    const float* xp = x + (((size_t)b * 128 + cqq * 4) * 128 + h) * 128 + p0 + px4 * 4;
    float4 v0 = *(const float4*)xp;
    float4 v1 = *(const float4*)(xp + HW);
    float4 v2 = *(const float4*)(xp + 2 * HW);
    float4 v3 = *(const float4*)(xp + 3 * HW);
    uint2* dst = &xpk[cqq * 64 + px4 * 4];
    uint2 w;
    w.x = pkrtz(v0.x, v1.x); w.y = pkrtz(v2.x, v3.x); dst[0] = w;
    w.x = pkrtz(v0.y, v1.y); w.y = pkrtz(v2.y, v3.y); dst[1] = w;
    w.x = pkrtz(v0.z, v1.z); w.y = pkrtz(v2.z, v3.z); dst[2] = w;
    w.x = pkrtz(v0.w, v1.w); w.y = pkrtz(v2.w, v3.w); dst[3] = w;
  }
  __syncthreads();

  // x16[b][h][px][c] channel-last
  uint4* xrow = (uint4*)(x16 + (((size_t)b * 128 + h) * 128 + p0) * 128);
#pragma unroll
  for (int it = 0; it < 4; it++) {
    int u = it * 256 + tid;
    int oct = u & 15, px = u >> 4;    // px 0..63
    uint2 a = xpk[(2 * oct) * 64 + px];
    uint2 c = xpk[(2 * oct + 1) * 64 + px];
    uint4 qv; qv.x = a.x; qv.y = a.y; qv.z = c.x; qv.w = c.y;
    xrow[px * 16 + oct] = qv;
  }

  floatx4 acc[5];
#pragma unroll
  for (int mt = 0; mt < 5; mt++) acc[mt] = (floatx4)0.f;
  const h8* A = (const h8*)woff;
  int q = lane >> 4, col = lane & 15;
  int pxl = wv * 16 + col;
#pragma unroll
  for (int ks = 0; ks < 4; ks++) {
    uint2 lo = xpk[(ks * 8 + 2 * q) * 64 + pxl];
    uint2 hi = xpk[(ks * 8 + 2 * q + 1) * 64 + pxl];
    uint4 qq; qq.x = lo.x; qq.y = lo.y; qq.z = hi.x; qq.w = hi.y;
    h8 bv = __builtin_bit_cast(h8, qq);
#pragma unroll
    for (int mt = 0; mt < 5; mt++)
      acc[mt] = __builtin_amdgcn_mfma_f32_16x16x32_f16(A[(ks * 5 + mt) * 64 + lane], bv, acc[mt], 0, 0, 0);
  }
#pragma unroll
  for (int mt = 0; mt < 5; mt++) {
    if (mt == 4 && q >= 2) continue;   // rows 72..79 padding
    int o0 = mt * 16 + q * 4;
    float4 bo = *(const float4*)(b_off + o0);
    floatx4 f = acc[mt];
    unsigned* dst = offs2 + ((size_t)b * 36 + (o0 >> 1)) * HW + h * 128 + p0 + pxl;
    dst[0]  = pkrtz(f[0] + bo.x, f[1] + bo.y);
    dst[HW] = pkrtz(f[2] + bo.z, f[3] + bo.w);
  }
}

// ---------------- kernel 2: deform conv ----------------
// grid 512 = (b,h) full row. Wave = 32 px (frags f=0,1). 5-row slab, no pad.
__global__ __launch_bounds__(256, 3) void deform_conv(
    const _Float16* __restrict__ x16, const _Float16* __restrict__ wdef,
    const unsigned* __restrict__ offs2, float* __restrict__ out) {
  __shared__ uint4 xs[5 * 128 * 5];     // [r][px][slot(4 used)] 51200 B

  int tid = threadIdx.x, lane = tid & 63, wv = tid >> 6;
  int i = blockIdx.x;
  int L = (i & 7) * 64 + (i >> 3);      // XCD band swizzle
  int b = L >> 7, h = L & 127;
  int rlo = min(max(h - 2, 0), 123);    // staged rows rlo..rlo+4
  int pa = 32 * wv + (lane & 15);       // frag-0 pixel (global col)
  int q = lane >> 4;                    // k-octet

  floatx4 acc[2][8];
#pragma unroll
  for (int f = 0; f < 2; f++)
#pragma unroll
    for (int ot = 0; ot < 8; ot++) acc[f][ot] = (floatx4)0.f;

  for (int t = 0; t < 4; t++) {         // group t: channels [32t, 32t+32)
    __syncthreads();                    // prev group's gathers done
    // ---- preload offsets for 9 kk x 2 frags (registers) ----
    unsigned dd[9][2];
#pragma unroll
    for (int kk = 0; kk < 9; kk++)
#pragma unroll
      for (int f = 0; f < 2; f++)
        dd[kk][f] = offs2[((size_t)b * 36 + t * 9 + kk) * HW + h * 128 + pa + 16 * f];
    // ---- stage 32ch x 5r x 128px from x16 -> xs (exactly 10/thread) ----
#pragma unroll
    for (int it = 0; it < 10; it++) {
      int u = tid + it * 256;
      int oct = u & 3, v2 = u >> 2;
      int px = v2 & 127, r = v2 >> 7;
      const uint4* src = (const uint4*)(x16 + (((size_t)b * 128 + rlo + r) * 128 + px) * 128 + t * 32) + oct;
      xs[(r * 128 + px) * 5 + oct] = *src;
    }
    __syncthreads();

    // ---- 9 kk phases: records in regs -> gather x2 -> 16 MFMA ----
#pragma unroll
    for (int kk = 0; kk < 9; kk++) {
      const uint4* Ak = (const uint4*)wdef + (size_t)(kk * 2048 + t * 512);
      h8 av[8];
#pragma unroll
      for (int ot = 0; ot < 8; ot++) av[ot] = __builtin_bit_cast(h8, Ak[ot * 64 + lane]);
#pragma unroll
      for (int f = 0; f < 2; f++) {
        int p = pa + 16 * f;
        h2 d = u2h2(dd[kk][f]);
        float dy = (float)d[0], dx = (float)d[1];
        float py = (float)h + (float)(kk / 3 - 1) + dy;
        float pxs = (float)p + (float)(kk % 3 - 1) + dx;
        float y0f = floorf(py), x0f = floorf(pxs);
        int y0 = (int)y0f, x0 = (int)x0f;
        float wy1f = py - y0f, wx1 = pxs - x0f;
        float wy0f = 1.f - wy1f, wx0 = 1.f - wx1;
        int x1 = x0 + 1, y1 = y0 + 1;
        int xb = min(max(x0, 0), 126);
        float fx0 = (x0 >= 0 && x0 <= 127) ? 1.f : 0.f;
        float fx1 = (x1 >= 0 && x1 <= 127) ? 1.f : 0.f;
        float wAf = (x0 == xb ? wx0 * fx0 : 0.f) + (x1 == xb ? wx1 * fx1 : 0.f);
        float wBf = (x0 == xb + 1 ? wx0 * fx0 : 0.f) + (x1 == xb + 1 ? wx1 * fx1 : 0.f);
        float fy0 = (y0 >= 0 && y0 <= 127) ? 1.f : 0.f;
        float fy1 = (y1 >= 0 && y1 <= 127) ? 1.f : 0.f;
        int r0 = min(max(min(max(y0, 0), 127) - rlo, 0), 4);
        int r1 = min(max(min(max(y1, 0), 127) - rlo, 0), 4);
        // combined corner weights (6->4 pk-ops per component in gather)
        float wy0e = wy0f * fy0, wy1e = wy1f * fy1;
        unsigned w0_pk = pkrtz(wy0e * wAf, wy0e * wBf);   // (w00, w01)
        unsigned w1_pk = pkrtz(wy1e * wAf, wy1e * wBf);   // (w10, w11)

        int i0 = (r0 * 128 + xb) * 5 + q;
        int i1 = (r1 * 128 + xb) * 5 + q;
        uint4 P = xs[i0], Q = xs[i0 + 5], R = xs[i1], S = xs[i1 + 5];
        h2 w00 = splat_lo(w0_pk), w01 = splat_hi(w0_pk);
        h2 w10 = splat_lo(w1_pk), w11 = splat_hi(w1_pk);
        uint4 bq;
        bq.x = h2u(w00 * u2h2(P.x) + w01 * u2h2(Q.x) + w10 * u2h2(R.x) + w11 * u2h2(S.x));
        bq.y = h2u(w00 * u2h2(P.y) + w01 * u2h2(Q.y) + w10 * u2h2(R.y) + w11 * u2h2(S.y));
        bq.z = h2u(w00 * u2h2(P.z) + w01 * u2h2(Q.z) + w10 * u2h2(R.z) + w11 * u2h2(S.z));
        bq.w = h2u(w00 * u2h2(P.w) + w01 * u2h2(Q.w) + w10 * u2h2(R.w) + w11 * u2h2(S.w));
        h8 bv = __builtin_bit_cast(h8, bq);
#pragma unroll
        for (int ot = 0; ot < 8; ot++)
          acc[f][ot] = __builtin_amdgcn_mfma_f32_16x16x32_f16(av[ot], bv, acc[f][ot], 0, 0, 0);
      }
    }
  }

  // ---- epilogue: C/D col=lane&15 (px), row=(lane>>4)*4+reg (o); ReLU ----
#pragma unroll
  for (int f = 0; f < 2; f++) {
    float* ob = out + (size_t)b * 128 * HW + h * 128 + pa + 16 * f;
#pragma unroll
    for (int ot = 0; ot < 8; ot++) {
      floatx4 fv = acc[f][ot];
#pragma unroll
      for (int reg = 0; reg < 4; reg++) {
        int o = ot * 16 + q * 4 + reg;
        ob[(size_t)o * HW] = fmaxf(fv[reg], 0.f);
      }
    }
  }
}

extern "C" void kernel_launch(void* const* d_in, const int* in_sizes, int n_in,
                              void* d_out, int out_size, void* d_ws, size_t ws_size,
                              hipStream_t stream) {
  const float* x     = (const float*)d_in[0];
  const float* w_off = (const float*)d_in[1];
  const float* b_off = (const float*)d_in[2];
  const float* w_def = (const float*)d_in[3];
  float* out = (float*)d_out;

  _Float16* wdef = (_Float16*)d_ws;                          // 294912 B
  _Float16* woff = (_Float16*)((char*)d_ws + 294912);        // 20480 B
  unsigned* offs2 = (unsigned*)((char*)d_ws + 315392);       // 9437184 B
  _Float16* x16  = (_Float16*)((char*)d_ws + 9752576);       // 16777216 B

  prep_w<<<dim3(288), dim3(256), 0, stream>>>(w_off, w_def, woff, wdef);
  prep_row<<<dim3(1024), dim3(256), 0, stream>>>(x, woff, b_off, offs2, x16);
  deform_conv<<<dim3(512), dim3(256), 0, stream>>>(x16, wdef, offs2, out);
}

// Round 11
// 131.200 us; speedup vs baseline: 1.1683x; 1.1683x over previous
//
#include <hip/hip_runtime.h>
#include <hip/hip_fp16.h>

// FeatureAdaption (DCNv1). B=4, CIN=COUT=128, H=W=128, K=3, G=4, CG=32.
// Round 11: r9 occupancy config (launch_bounds(256,2) -- r10's (256,3) cap
// minus 64 AGPR accumulators left ~104 arch VGPRs -> spills, WRITE_SIZE 74MB)
// + wave-local LDS record sharing (kills the 4x-redundant record VALU that
// made VALUBusy=45% the top pipe in r9; same-wave ds write->read needs NO
// block barrier).
//  - deform: grid 512 = (b,h) row; wave = 32 px (2 B-frags); 5-row slab,
//    xs[r5][px128][slot5(4 used)] stride-5 -> all-8-bank-group gather.
//  - records: per wave 288 = 9kk x 32px distributed over 64 lanes (5 iters),
//    stored {uint2 weights, u16x2 indices} in per-wave LDS slice (13.8 KB).
//    LDS total 65,024 B (fits 64 KB WG limit), 2 blocks/CU (grid-capped).
//
// ws layout (bytes): wdef [0,294912) | woff [294912,315392)
//   | offs2 [315392,9752576) | x16 [9752576,26529792)

#define HW 16384

typedef _Float16 h2 __attribute__((ext_vector_type(2)));
typedef _Float16 h8 __attribute__((ext_vector_type(8)));
typedef float floatx4 __attribute__((ext_vector_type(4)));

static __device__ __forceinline__ unsigned pkrtz(float a, float b) {
  auto h = __builtin_amdgcn_cvt_pkrtz(a, b);
  return __builtin_bit_cast(unsigned, h);
}
static __device__ __forceinline__ h2 u2h2(unsigned u) { return __builtin_bit_cast(h2, u); }
static __device__ __forceinline__ unsigned h2u(h2 h) { return __builtin_bit_cast(unsigned, h); }
static __device__ __forceinline__ h2 splat_lo(unsigned u) {
  unsigned v = (u & 0xffffu) | (u << 16); return u2h2(v);
}
static __device__ __forceinline__ h2 splat_hi(unsigned u) {
  unsigned v = (u >> 16) | (u & 0xffff0000u); return u2h2(v);
}

// ---------------- kernel 0: weight prep ----------------
__global__ __launch_bounds__(256) void prep_w(
    const float* __restrict__ w_off, const float* __restrict__ w_def,
    _Float16* __restrict__ woff, _Float16* __restrict__ wdef) {
  int idx = blockIdx.x * 256 + threadIdx.x;
  int stride = gridDim.x * 256;
  // wdef A-frags (16x16x32): [kk9][ks4][ot8][lane64][j8]
  for (int i = idx; i < 147456; i += stride) {
    int j = i & 7, l = (i >> 3) & 63, ot = (i >> 9) & 7, ks = (i >> 12) & 3, kk = i >> 14;
    int o = ot * 16 + (l & 15);
    int c = ks * 32 + ((l >> 4) << 3) + j;
    wdef[i] = (_Float16)w_def[(o * 128 + c) * 9 + kk];
  }
  // woff A-frags (16x16x32): [ks4][mt5][lane64][j8], rows>=72 zero
  for (int i = idx; i < 10240; i += stride) {
    int j = i & 7, l = (i >> 3) & 63, t = i >> 9;
    int mt = t % 5, ks = t / 5;
    int o = mt * 16 + (l & 15);
    int c = ks * 32 + ((l >> 4) << 3) + j;
    woff[i] = (o < 72) ? (_Float16)w_off[o * 128 + c] : (_Float16)0.f;
  }
}

// ---------------- kernel 1: fused transpose + offset conv (half-row) ----------------
__global__ __launch_bounds__(256) void prep_row(
    const float* __restrict__ x, const _Float16* __restrict__ woff,
    const float* __restrict__ b_off, unsigned* __restrict__ offs2,
    _Float16* __restrict__ x16) {
  __shared__ uint2 xpk[32 * 64];    // [cq32][px64] f16 ch-quads, 16 KB
  int tid = threadIdx.x, lane = tid & 63, wv = tid >> 6;
  int i = blockIdx.x;
  int L = (i & 7) * 128 + (i >> 3); // XCD band swizzle
  int half = L & 1, h = (L >> 1) & 127, b = L >> 8;
  int p0 = half * 64;

#pragma unroll
  for (int it = 0; it < 2; it++) {
    int u = it * 256 + tid;
    int px4 = u & 15, cqq = u >> 4;   // 16 px-quads x 32 ch-quads
    const float* xp = x + (((size_t)b * 128 + cqq * 4) * 128 + h) * 128 + p0 + px4 * 4;
    float4 v0 = *(const float4*)xp;
    float4 v1 = *(const float4*)(xp + HW);
    float4 v2 = *(const float4*)(xp + 2 * HW);
    float4 v3 = *(const float4*)(xp + 3 * HW);
    uint2* dst = &xpk[cqq * 64 + px4 * 4];
    uint2 w;
    w.x = pkrtz(v0.x, v1.x); w.y = pkrtz(v2.x, v3.x); dst[0] = w;
    w.x = pkrtz(v0.y, v1.y); w.y = pkrtz(v2.y, v3.y); dst[1] = w;
    w.x = pkrtz(v0.z, v1.z); w.y = pkrtz(v2.z, v3.z); dst[2] = w;
    w.x = pkrtz(v0.w, v1.w); w.y = pkrtz(v2.w, v3.w); dst[3] = w;
  }
  __syncthreads();

  // x16[b][h][px][c] channel-last
  uint4* xrow = (uint4*)(x16 + (((size_t)b * 128 + h) * 128 + p0) * 128);
#pragma unroll
  for (int it = 0; it < 4; it++) {
    int u = it * 256 + tid;
    int oct = u & 15, px = u >> 4;    // px 0..63
    uint2 a = xpk[(2 * oct) * 64 + px];
    uint2 c = xpk[(2 * oct + 1) * 64 + px];
    uint4 qv; qv.x = a.x; qv.y = a.y; qv.z = c.x; qv.w = c.y;
    xrow[px * 16 + oct] = qv;
  }

  floatx4 acc[5];
#pragma unroll
  for (int mt = 0; mt < 5; mt++) acc[mt] = (floatx4)0.f;
  const h8* A = (const h8*)woff;
  int q = lane >> 4, col = lane & 15;
  int pxl = wv * 16 + col;
#pragma unroll
  for (int ks = 0; ks < 4; ks++) {
    uint2 lo = xpk[(ks * 8 + 2 * q) * 64 + pxl];
    uint2 hi = xpk[(ks * 8 + 2 * q + 1) * 64 + pxl];
    uint4 qq; qq.x = lo.x; qq.y = lo.y; qq.z = hi.x; qq.w = hi.y;
    h8 bv = __builtin_bit_cast(h8, qq);
#pragma unroll
    for (int mt = 0; mt < 5; mt++)
      acc[mt] = __builtin_amdgcn_mfma_f32_16x16x32_f16(A[(ks * 5 + mt) * 64 + lane], bv, acc[mt], 0, 0, 0);
  }
#pragma unroll
  for (int mt = 0; mt < 5; mt++) {
    if (mt == 4 && q >= 2) continue;   // rows 72..79 padding
    int o0 = mt * 16 + q * 4;
    float4 bo = *(const float4*)(b_off + o0);
    floatx4 f = acc[mt];
    unsigned* dst = offs2 + ((size_t)b * 36 + (o0 >> 1)) * HW + h * 128 + p0 + pxl;
    dst[0]  = pkrtz(f[0] + bo.x, f[1] + bo.y);
    dst[HW] = pkrtz(f[2] + bo.z, f[3] + bo.w);
  }
}

// ---------------- kernel 2: deform conv ----------------
// grid 512 = (b,h) full row. Wave = 32 px (frags f=0,1). 5-row slab.
__global__ __launch_bounds__(256, 2) void deform_conv(
    const _Float16* __restrict__ x16, const _Float16* __restrict__ wdef,
    const unsigned* __restrict__ offs2, float* __restrict__ out) {
  __shared__ uint4 xs[5 * 128 * 5];       // 51200 B [r][px][slot(4 used)]
  __shared__ uint2 rec_w[4][9][32];       // 9216 B  per-wave records (weights)
  __shared__ unsigned rec_i[4][9][32];    // 4608 B  per-wave records (i0|i1<<16)

  int tid = threadIdx.x, lane = tid & 63, wv = tid >> 6;
  int i = blockIdx.x;
  int L = (i & 7) * 64 + (i >> 3);      // XCD band swizzle
  int b = L >> 7, h = L & 127;
  int rlo = min(max(h - 2, 0), 123);    // staged rows rlo..rlo+4
  int q = lane >> 4;                    // k-octet
  int col = lane & 15;

  floatx4 acc[2][8];
#pragma unroll
  for (int f = 0; f < 2; f++)
#pragma unroll
    for (int ot = 0; ot < 8; ot++) acc[f][ot] = (floatx4)0.f;

  for (int t = 0; t < 4; t++) {         // group t: channels [32t, 32t+32)
    __syncthreads();                    // prev group's xs readers done
    // ---- wave-local records: 288 = 9kk x 32px over 64 lanes (no barrier) ----
#pragma unroll
    for (int it = 0; it < 5; it++) {
      int u = it * 64 + lane;
      if (u < 288) {
        int kk = u >> 5, pl = u & 31;
        int p = 32 * wv + pl;
        unsigned dd = offs2[((size_t)b * 36 + t * 9 + kk) * HW + h * 128 + p];
        h2 d = u2h2(dd);
        float dy = (float)d[0], dx = (float)d[1];
        float py = (float)h + (float)(kk / 3 - 1) + dy;
        float pxs = (float)p + (float)(kk % 3 - 1) + dx;
        float y0f = floorf(py), x0f = floorf(pxs);
        int y0 = (int)y0f, x0 = (int)x0f;
        float wy1f = py - y0f, wx1 = pxs - x0f;
        float wy0f = 1.f - wy1f, wx0 = 1.f - wx1;
        int x1 = x0 + 1, y1 = y0 + 1;
        int xb = min(max(x0, 0), 126);
        float fx0 = (x0 >= 0 && x0 <= 127) ? 1.f : 0.f;
        float fx1 = (x1 >= 0 && x1 <= 127) ? 1.f : 0.f;
        float wAf = (x0 == xb ? wx0 * fx0 : 0.f) + (x1 == xb ? wx1 * fx1 : 0.f);
        float wBf = (x0 == xb + 1 ? wx0 * fx0 : 0.f) + (x1 == xb + 1 ? wx1 * fx1 : 0.f);
        float fy0 = (y0 >= 0 && y0 <= 127) ? 1.f : 0.f;
        float fy1 = (y1 >= 0 && y1 <= 127) ? 1.f : 0.f;
        int r0 = min(max(min(max(y0, 0), 127) - rlo, 0), 4);
        int r1 = min(max(min(max(y1, 0), 127) - rlo, 0), 4);
        float wy0e = wy0f * fy0, wy1e = wy1f * fy1;
        uint2 rw;
        rw.x = pkrtz(wy0e * wAf, wy0e * wBf);   // (w00, w01)
        rw.y = pkrtz(wy1e * wAf, wy1e * wBf);   // (w10, w11)
        rec_w[wv][kk][pl] = rw;
        unsigned i0 = (unsigned)((r0 * 128 + xb) * 5);
        unsigned i1 = (unsigned)((r1 * 128 + xb) * 5);
        rec_i[wv][kk][pl] = i0 | (i1 << 16);
      }
    }
    // ---- stage 32ch x 5r x 128px from x16 -> xs (exactly 10/thread) ----
#pragma unroll
    for (int it = 0; it < 10; it++) {
      int u = tid + it * 256;
      int oct = u & 3, v2 = u >> 2;
      int px = v2 & 127, r = v2 >> 7;
      const uint4* src = (const uint4*)(x16 + (((size_t)b * 128 + rlo + r) * 128 + px) * 128 + t * 32) + oct;
      xs[(r * 128 + px) * 5 + oct] = *src;
    }
    __syncthreads();

    // ---- 9 kk phases: rec read (wave-local) -> gather x2 -> 16 MFMA ----
#pragma unroll
    for (int kk = 0; kk < 9; kk++) {
      const uint4* Ak = (const uint4*)wdef + (size_t)(kk * 2048 + t * 512);
      h8 av[8];
#pragma unroll
      for (int ot = 0; ot < 8; ot++) av[ot] = __builtin_bit_cast(h8, Ak[ot * 64 + lane]);
#pragma unroll
      for (int f = 0; f < 2; f++) {
        int sl = 16 * f + col;
        uint2 rw = rec_w[wv][kk][sl];        // quad-broadcast b64
        unsigned ii = rec_i[wv][kk][sl];
        int i0 = (int)(ii & 0xffffu) + q;
        int i1 = (int)(ii >> 16) + q;
        uint4 P = xs[i0], Q = xs[i0 + 5], R = xs[i1], S = xs[i1 + 5];
        h2 w00 = splat_lo(rw.x), w01 = splat_hi(rw.x);
        h2 w10 = splat_lo(rw.y), w11 = splat_hi(rw.y);
        uint4 bq;
        bq.x = h2u(w00 * u2h2(P.x) + w01 * u2h2(Q.x) + w10 * u2h2(R.x) + w11 * u2h2(S.x));
        bq.y = h2u(w00 * u2h2(P.y) + w01 * u2h2(Q.y) + w10 * u2h2(R.y) + w11 * u2h2(S.y));
        bq.z = h2u(w00 * u2h2(P.z) + w01 * u2h2(Q.z) + w10 * u2h2(R.z) + w11 * u2h2(S.z));
        bq.w = h2u(w00 * u2h2(P.w) + w01 * u2h2(Q.w) + w10 * u2h2(R.w) + w11 * u2h2(S.w));
        h8 bv = __builtin_bit_cast(h8, bq);
#pragma unroll
        for (int ot = 0; ot < 8; ot++)
          acc[f][ot] = __builtin_amdgcn_mfma_f32_16x16x32_f16(av[ot], bv, acc[f][ot], 0, 0, 0);
      }
    }
  }

  // ---- epilogue: C/D col=lane&15 (px), row=(lane>>4)*4+reg (o); ReLU ----
#pragma unroll
  for (int f = 0; f < 2; f++) {
    float* ob = out + (size_t)b * 128 * HW + h * 128 + 32 * wv + col + 16 * f;
#pragma unroll
    for (int ot = 0; ot < 8; ot++) {
      floatx4 fv = acc[f][ot];
#pragma unroll
      for (int reg = 0; reg < 4; reg++) {
        int o = ot * 16 + q * 4 + reg;
        ob[(size_t)o * HW] = fmaxf(fv[reg], 0.f);
      }
    }
  }
}

extern "C" void kernel_launch(void* const* d_in, const int* in_sizes, int n_in,
                              void* d_out, int out_size, void* d_ws, size_t ws_size,
                              hipStream_t stream) {
  const float* x     = (const float*)d_in[0];
  const float* w_off = (const float*)d_in[1];
  const float* b_off = (const float*)d_in[2];
  const float* w_def = (const float*)d_in[3];
  float* out = (float*)d_out;

  _Float16* wdef = (_Float16*)d_ws;                          // 294912 B
  _Float16* woff = (_Float16*)((char*)d_ws + 294912);        // 20480 B
  unsigned* offs2 = (unsigned*)((char*)d_ws + 315392);       // 9437184 B
  _Float16* x16  = (_Float16*)((char*)d_ws + 9752576);       // 16777216 B

  prep_w<<<dim3(288), dim3(256), 0, stream>>>(w_off, w_def, woff, wdef);
  prep_row<<<dim3(1024), dim3(256), 0, stream>>>(x, woff, b_off, offs2, x16);
  deform_conv<<<dim3(512), dim3(256), 0, stream>>>(x16, wdef, offs2, out);
}

// Round 12
// 130.737 us; speedup vs baseline: 1.1724x; 1.0035x over previous
//
#include <hip/hip_runtime.h>
#include <hip/hip_fp16.h>

// FeatureAdaption (DCNv1). B=4, CIN=COUT=128, H=W=128, K=3, G=4, CG=32.
// Round 12: r11 + LDS shrink 65->52.5 KB => 3 blocks/CU (hardware-scheduled;
// launch_bounds stays (256,2) -- r10 showed forcing 3 waves/EU spills with
// 64 AGPR accumulators, but at 108 arch VGPRs the HW gives 3 blocks once
// LDS fits).
//  - xs: 4 slots + XOR swizzle slot=oct^(px&3): bank-group 4(px&1)+q^(px&3)
//    uniform (8 lanes/group = b128 minimum) for staging AND gather. 40960 B.
//  - rec_i: ushort/record: i0=(r0*128+xb)*4 (12 bits) | (r1>r0)<<12;
//    i1 = i0 + 512*flag; xb&3 for swizzle = (i0>>2)&3. 2304 B.
//  - LDS 40960+9216+2304 = 52480 B -> 3 blocks/CU.
//
// ws layout (bytes): wdef [0,294912) | woff [294912,315392)
//   | offs2 [315392,9752576) | x16 [9752576,26529792)

#define HW 16384

typedef _Float16 h2 __attribute__((ext_vector_type(2)));
typedef _Float16 h8 __attribute__((ext_vector_type(8)));
typedef float floatx4 __attribute__((ext_vector_type(4)));

static __device__ __forceinline__ unsigned pkrtz(float a, float b) {
  auto h = __builtin_amdgcn_cvt_pkrtz(a, b);
  return __builtin_bit_cast(unsigned, h);
}
static __device__ __forceinline__ h2 u2h2(unsigned u) { return __builtin_bit_cast(h2, u); }
static __device__ __forceinline__ unsigned h2u(h2 h) { return __builtin_bit_cast(unsigned, h); }
static __device__ __forceinline__ h2 splat_lo(unsigned u) {
  unsigned v = (u & 0xffffu) | (u << 16); return u2h2(v);
}
static __device__ __forceinline__ h2 splat_hi(unsigned u) {
  unsigned v = (u >> 16) | (u & 0xffff0000u); return u2h2(v);
}

// ---------------- kernel 0: weight prep ----------------
__global__ __launch_bounds__(256) void prep_w(
    const float* __restrict__ w_off, const float* __restrict__ w_def,
    _Float16* __restrict__ woff, _Float16* __restrict__ wdef) {
  int idx = blockIdx.x * 256 + threadIdx.x;
  int stride = gridDim.x * 256;
  // wdef A-frags (16x16x32): [kk9][ks4][ot8][lane64][j8]
  for (int i = idx; i < 147456; i += stride) {
    int j = i & 7, l = (i >> 3) & 63, ot = (i >> 9) & 7, ks = (i >> 12) & 3, kk = i >> 14;
    int o = ot * 16 + (l & 15);
    int c = ks * 32 + ((l >> 4) << 3) + j;
    wdef[i] = (_Float16)w_def[(o * 128 + c) * 9 + kk];
  }
  // woff A-frags (16x16x32): [ks4][mt5][lane64][j8], rows>=72 zero
  for (int i = idx; i < 10240; i += stride) {
    int j = i & 7, l = (i >> 3) & 63, t = i >> 9;
    int mt = t % 5, ks = t / 5;
    int o = mt * 16 + (l & 15);
    int c = ks * 32 + ((l >> 4) << 3) + j;
    woff[i] = (o < 72) ? (_Float16)w_off[o * 128 + c] : (_Float16)0.f;
  }
}

// ---------------- kernel 1: fused transpose + offset conv (half-row) ----------------
__global__ __launch_bounds__(256) void prep_row(
    const float* __restrict__ x, const _Float16* __restrict__ woff,
    const float* __restrict__ b_off, unsigned* __restrict__ offs2,
    _Float16* __restrict__ x16) {
  __shared__ uint2 xpk[32 * 64];    // [cq32][px64] f16 ch-quads, 16 KB
  int tid = threadIdx.x, lane = tid & 63, wv = tid >> 6;
  int i = blockIdx.x;
  int L = (i & 7) * 128 + (i >> 3); // XCD band swizzle
  int half = L & 1, h = (L >> 1) & 127, b = L >> 8;
  int p0 = half * 64;

#pragma unroll
  for (int it = 0; it < 2; it++) {
    int u = it * 256 + tid;
    int px4 = u & 15, cqq = u >> 4;   // 16 px-quads x 32 ch-quads
    const float* xp = x + (((size_t)b * 128 + cqq * 4) * 128 + h) * 128 + p0 + px4 * 4;
    float4 v0 = *(const float4*)xp;
    float4 v1 = *(const float4*)(xp + HW);
    float4 v2 = *(const float4*)(xp + 2 * HW);
    float4 v3 = *(const float4*)(xp + 3 * HW);
    uint2* dst = &xpk[cqq * 64 + px4 * 4];
    uint2 w;
    w.x = pkrtz(v0.x, v1.x); w.y = pkrtz(v2.x, v3.x); dst[0] = w;
    w.x = pkrtz(v0.y, v1.y); w.y = pkrtz(v2.y, v3.y); dst[1] = w;
    w.x = pkrtz(v0.z, v1.z); w.y = pkrtz(v2.z, v3.z); dst[2] = w;
    w.x = pkrtz(v0.w, v1.w); w.y = pkrtz(v2.w, v3.w); dst[3] = w;
  }
  __syncthreads();

  // x16[b][h][px][c] channel-last
  uint4* xrow = (uint4*)(x16 + (((size_t)b * 128 + h) * 128 + p0) * 128);
#pragma unroll
  for (int it = 0; it < 4; it++) {
    int u = it * 256 + tid;
    int oct = u & 15, px = u >> 4;    // px 0..63
    uint2 a = xpk[(2 * oct) * 64 + px];
    uint2 c = xpk[(2 * oct + 1) * 64 + px];
    uint4 qv; qv.x = a.x; qv.y = a.y; qv.z = c.x; qv.w = c.y;
    xrow[px * 16 + oct] = qv;
  }

  floatx4 acc[5];
#pragma unroll
  for (int mt = 0; mt < 5; mt++) acc[mt] = (floatx4)0.f;
  const h8* A = (const h8*)woff;
  int q = lane >> 4, col = lane & 15;
  int pxl = wv * 16 + col;
#pragma unroll
  for (int ks = 0; ks < 4; ks++) {
    uint2 lo = xpk[(ks * 8 + 2 * q) * 64 + pxl];
    uint2 hi = xpk[(ks * 8 + 2 * q + 1) * 64 + pxl];
    uint4 qq; qq.x = lo.x; qq.y = lo.y; qq.z = hi.x; qq.w = hi.y;
    h8 bv = __builtin_bit_cast(h8, qq);
#pragma unroll
    for (int mt = 0; mt < 5; mt++)
      acc[mt] = __builtin_amdgcn_mfma_f32_16x16x32_f16(A[(ks * 5 + mt) * 64 + lane], bv, acc[mt], 0, 0, 0);
  }
#pragma unroll
  for (int mt = 0; mt < 5; mt++) {
    if (mt == 4 && q >= 2) continue;   // rows 72..79 padding
    int o0 = mt * 16 + q * 4;
    float4 bo = *(const float4*)(b_off + o0);
    floatx4 f = acc[mt];
    unsigned* dst = offs2 + ((size_t)b * 36 + (o0 >> 1)) * HW + h * 128 + p0 + pxl;
    dst[0]  = pkrtz(f[0] + bo.x, f[1] + bo.y);
    dst[HW] = pkrtz(f[2] + bo.z, f[3] + bo.w);
  }
}

// ---------------- kernel 2: deform conv ----------------
// grid 512 = (b,h) full row. Wave = 32 px (frags f=0,1). 5-row slab.
__global__ __launch_bounds__(256, 2) void deform_conv(
    const _Float16* __restrict__ x16, const _Float16* __restrict__ wdef,
    const unsigned* __restrict__ offs2, float* __restrict__ out) {
  __shared__ uint4 xs[5 * 128 * 4];       // 40960 B, slot = oct^(px&3)
  __shared__ uint2 rec_w[4][9][32];       // 9216 B  (w00,w01),(w10,w11) f16
  __shared__ unsigned short rec_i[4][9][32]; // 2304 B  i0(12b) | (r1>r0)<<12

  int tid = threadIdx.x, lane = tid & 63, wv = tid >> 6;
  int i = blockIdx.x;
  int L = (i & 7) * 64 + (i >> 3);      // XCD band swizzle
  int b = L >> 7, h = L & 127;
  int rlo = min(max(h - 2, 0), 123);    // staged rows rlo..rlo+4
  int q = lane >> 4;                    // k-octet
  int col = lane & 15;

  floatx4 acc[2][8];
#pragma unroll
  for (int f = 0; f < 2; f++)
#pragma unroll
    for (int ot = 0; ot < 8; ot++) acc[f][ot] = (floatx4)0.f;

  for (int t = 0; t < 4; t++) {         // group t: channels [32t, 32t+32)
    __syncthreads();                    // prev group's xs readers done
    // ---- wave-local records: 288 = 9kk x 32px over 64 lanes (no barrier) ----
#pragma unroll
    for (int it = 0; it < 5; it++) {
      int u = it * 64 + lane;
      if (u < 288) {
        int kk = u >> 5, pl = u & 31;
        int p = 32 * wv + pl;
        unsigned dd = offs2[((size_t)b * 36 + t * 9 + kk) * HW + h * 128 + p];
        h2 d = u2h2(dd);
        float dy = (float)d[0], dx = (float)d[1];
        float py = (float)h + (float)(kk / 3 - 1) + dy;
        float pxs = (float)p + (float)(kk % 3 - 1) + dx;
        float y0f = floorf(py), x0f = floorf(pxs);
        int y0 = (int)y0f, x0 = (int)x0f;
        float wy1f = py - y0f, wx1 = pxs - x0f;
        float wy0f = 1.f - wy1f, wx0 = 1.f - wx1;
        int x1 = x0 + 1, y1 = y0 + 1;
        int xb = min(max(x0, 0), 126);
        float fx0 = (x0 >= 0 && x0 <= 127) ? 1.f : 0.f;
        float fx1 = (x1 >= 0 && x1 <= 127) ? 1.f : 0.f;
        float wAf = (x0 == xb ? wx0 * fx0 : 0.f) + (x1 == xb ? wx1 * fx1 : 0.f);
        float wBf = (x0 == xb + 1 ? wx0 * fx0 : 0.f) + (x1 == xb + 1 ? wx1 * fx1 : 0.f);
        float fy0 = (y0 >= 0 && y0 <= 127) ? 1.f : 0.f;
        float fy1 = (y1 >= 0 && y1 <= 127) ? 1.f : 0.f;
        int r0 = min(max(min(max(y0, 0), 127) - rlo, 0), 4);
        int r1 = min(max(min(max(y1, 0), 127) - rlo, 0), 4);
        float wy0e = wy0f * fy0, wy1e = wy1f * fy1;
        uint2 rw;
        rw.x = pkrtz(wy0e * wAf, wy0e * wBf);   // (w00, w01)
        rw.y = pkrtz(wy1e * wAf, wy1e * wBf);   // (w10, w11)
        rec_w[wv][kk][pl] = rw;
        unsigned i0 = (unsigned)((r0 * 128 + xb) * 4);       // 12 bits
        unsigned dflag = (unsigned)(r1 > r0);
        rec_i[wv][kk][pl] = (unsigned short)(i0 | (dflag << 12));
      }
    }
    // ---- stage 32ch x 5r x 128px from x16 -> xs (exactly 10/thread) ----
#pragma unroll
    for (int it = 0; it < 10; it++) {
      int u = tid + it * 256;
      int oct = u & 3, v2 = u >> 2;
      int px = v2 & 127, r = v2 >> 7;
      const uint4* src = (const uint4*)(x16 + (((size_t)b * 128 + rlo + r) * 128 + px) * 128 + t * 32) + oct;
      xs[(r * 128 + px) * 4 + (oct ^ (px & 3))] = *src;
    }
    __syncthreads();

    // ---- 9 kk phases: rec read (wave-local) -> gather x2 -> 16 MFMA ----
#pragma unroll
    for (int kk = 0; kk < 9; kk++) {
      const uint4* Ak = (const uint4*)wdef + (size_t)(kk * 2048 + t * 512);
      h8 av[8];
#pragma unroll
      for (int ot = 0; ot < 8; ot++) av[ot] = __builtin_bit_cast(h8, Ak[ot * 64 + lane]);
#pragma unroll
      for (int f = 0; f < 2; f++) {
        int sl = 16 * f + col;
        uint2 rw = rec_w[wv][kk][sl];        // quad-broadcast b64
        unsigned ii = rec_i[wv][kk][sl];
        int i0 = (int)(ii & 0xFFFu);
        int i1 = i0 + (int)((ii >> 12) << 9);      // +512 if r1>r0
        int xbm = (i0 >> 2) & 3;
        int sP = q ^ xbm;
        int sQ = q ^ ((xbm + 1) & 3);
        uint4 P = xs[i0 + sP], Q = xs[i0 + 4 + sQ];
        uint4 R = xs[i1 + sP], S = xs[i1 + 4 + sQ];
        h2 w00 = splat_lo(rw.x), w01 = splat_hi(rw.x);
        h2 w10 = splat_lo(rw.y), w11 = splat_hi(rw.y);
        uint4 bq;
        bq.x = h2u(w00 * u2h2(P.x) + w01 * u2h2(Q.x) + w10 * u2h2(R.x) + w11 * u2h2(S.x));
        bq.y = h2u(w00 * u2h2(P.y) + w01 * u2h2(Q.y) + w10 * u2h2(R.y) + w11 * u2h2(S.y));
        bq.z = h2u(w00 * u2h2(P.z) + w01 * u2h2(Q.z) + w10 * u2h2(R.z) + w11 * u2h2(S.z));
        bq.w = h2u(w00 * u2h2(P.w) + w01 * u2h2(Q.w) + w10 * u2h2(R.w) + w11 * u2h2(S.w));
        h8 bv = __builtin_bit_cast(h8, bq);
#pragma unroll
        for (int ot = 0; ot < 8; ot++)
          acc[f][ot] = __builtin_amdgcn_mfma_f32_16x16x32_f16(av[ot], bv, acc[f][ot], 0, 0, 0);
      }
    }
  }

  // ---- epilogue: C/D col=lane&15 (px), row=(lane>>4)*4+reg (o); ReLU ----
#pragma unroll
  for (int f = 0; f < 2; f++) {
    float* ob = out + (size_t)b * 128 * HW + h * 128 + 32 * wv + col + 16 * f;
#pragma unroll
    for (int ot = 0; ot < 8; ot++) {
      floatx4 fv = acc[f][ot];
#pragma unroll
      for (int reg = 0; reg < 4; reg++) {
        int o = ot * 16 + q * 4 + reg;
        ob[(size_t)o * HW] = fmaxf(fv[reg], 0.f);
      }
    }
  }
}

extern "C" void kernel_launch(void* const* d_in, const int* in_sizes, int n_in,
                              void* d_out, int out_size, void* d_ws, size_t ws_size,
                              hipStream_t stream) {
  const float* x     = (const float*)d_in[0];
  const float* w_off = (const float*)d_in[1];
  const float* b_off = (const float*)d_in[2];
  const float* w_def = (const float*)d_in[3];
  float* out = (float*)d_out;

  _Float16* wdef = (_Float16*)d_ws;                          // 294912 B
  _Float16* woff = (_Float16*)((char*)d_ws + 294912);        // 20480 B
  unsigned* offs2 = (unsigned*)((char*)d_ws + 315392);       // 9437184 B
  _Float16* x16  = (_Float16*)((char*)d_ws + 9752576);       // 16777216 B

  prep_w<<<dim3(288), dim3(256), 0, stream>>>(w_off, w_def, woff, wdef);
  prep_row<<<dim3(1024), dim3(256), 0, stream>>>(x, woff, b_off, offs2, x16);
  deform_conv<<<dim3(512), dim3(256), 0, stream>>>(x16, wdef, offs2, out);
}